// Round 1
// baseline (370.816 us; speedup 1.0000x reference)
//
#include <hip/hip_runtime.h>
#include <stdint.h>

typedef unsigned short u16;
typedef __bf16 bf16x8 __attribute__((ext_vector_type(8)));
typedef float f32x4 __attribute__((ext_vector_type(4)));
typedef unsigned short u16x8 __attribute__((ext_vector_type(8)));
typedef unsigned short u16x4 __attribute__((ext_vector_type(4)));

__device__ __forceinline__ u16 f2bf(float f) {
  union { float f; uint32_t u; } x; x.f = f;
  uint32_t r = x.u + 0x7fffu + ((x.u >> 16) & 1u);   // RNE
  return (u16)(r >> 16);
}

// ---------- prologue: A fp32 -> bf16 ----------
__global__ __launch_bounds__(256) void cvt_a(const float* __restrict__ A,
                                             u16* __restrict__ Ab, size_t n8) {
  size_t i = (size_t)blockIdx.x * 256 + threadIdx.x;
  if (i >= n8) return;
  const float4* p = (const float4*)(A + i * 8);
  float4 v0 = p[0], v1 = p[1];
  u16x8 r = { f2bf(v0.x), f2bf(v0.y), f2bf(v0.z), f2bf(v0.w),
              f2bf(v1.x), f2bf(v1.y), f2bf(v1.z), f2bf(v1.w) };
  *(u16x8*)(Ab + i * 8) = r;
}

// ---------- prologue: W int32 q8_0 -> bf16 (scale folded) ----------
__global__ __launch_bounds__(256) void cvt_w(const int* __restrict__ Wq,
                                             const float* __restrict__ S,
                                             u16* __restrict__ Wb, size_t n8) {
  size_t i = (size_t)blockIdx.x * 256 + threadIdx.x;
  if (i >= n8) return;
  const int4* p = (const int4*)(Wq + i * 8);
  int4 v0 = p[0], v1 = p[1];
  float s = S[i >> 2];  // (i*8)/32 — 8 consecutive elems share one 32-block
  u16x8 r = { f2bf((float)(v0.x - 128) * s), f2bf((float)(v0.y - 128) * s),
              f2bf((float)(v0.z - 128) * s), f2bf((float)(v0.w - 128) * s),
              f2bf((float)(v1.x - 128) * s), f2bf((float)(v1.y - 128) * s),
              f2bf((float)(v1.z - 128) * s), f2bf((float)(v1.w - 128) * s) };
  *(u16x8*)(Wb + i * 8) = r;
}

// ---------- main GEMM: C[M,N] = A[M,K] * W[N,K]^T, bf16 MFMA ----------
#define BM 128
#define BN 128
#define BK 32

__device__ __forceinline__ void load_lds_16B(const void* g, void* l) {
  __builtin_amdgcn_global_load_lds(
      (const __attribute__((address_space(1))) unsigned int*)g,
      (__attribute__((address_space(3))) unsigned int*)l, 16, 0, 0);
}

template <bool PRE>
__global__ __launch_bounds__(256) void gemm_bt(
    const u16* __restrict__ Ab, const u16* __restrict__ Wb,
    const float* __restrict__ Af, const int* __restrict__ Wq,
    const float* __restrict__ S, float* __restrict__ C,
    int M, int N, int K) {
  __shared__ u16 As[BM * BK];  // [row][k], row stride 32 bf16 = 64 B
  __shared__ u16 Bs[BN * BK];

  const int tid = threadIdx.x;
  const int wave = tid >> 6, lane = tid & 63;
  const int m0 = blockIdx.y * BM, n0 = blockIdx.x * BN;
  const int wm = (wave & 1) * 64, wn = (wave >> 1) * 64;
  const int lrow = lane & 15, lq = lane >> 4;

  f32x4 acc[4][4] = {};

  for (int k0 = 0; k0 < K; k0 += BK) {
    if constexpr (PRE) {
      // async global->LDS, 16 B/lane; LDS dest = wave-uniform base + lane*16
      #pragma unroll
      for (int it = 0; it < 2; ++it) {
        int c = wave * 2 + it;       // 0..7 across block
        int q0 = c * 64;             // flat 16B-chunk index of lane 0
        int q = q0 + lane;
        int row = q >> 2, c16 = q & 3;  // 4 chunks of 16B per 64 B row
        load_lds_16B(Ab + (size_t)(m0 + row) * K + k0 + c16 * 8, As + q0 * 8);
        load_lds_16B(Wb + (size_t)(n0 + row) * K + k0 + c16 * 8, Bs + q0 * 8);
      }
    } else {
      // fused fallback: load fp32/int32, convert in VGPRs, ds_write
      #pragma unroll
      for (int it = 0; it < 4; ++it) {
        int f = it * 256 + tid;      // float4/int4 index in tile (1024 total)
        int row = f >> 3, c4 = f & 7;
        const float4 va = *(const float4*)(Af + (size_t)(m0 + row) * K + k0 + c4 * 4);
        u16x4 ra = { f2bf(va.x), f2bf(va.y), f2bf(va.z), f2bf(va.w) };
        *(u16x4*)(&As[row * BK + c4 * 4]) = ra;
        const int4 vb = *(const int4*)(Wq + (size_t)(n0 + row) * K + k0 + c4 * 4);
        const float s = S[(size_t)(n0 + row) * (K >> 5) + (k0 >> 5)];
        u16x4 rb = { f2bf((float)(vb.x - 128) * s), f2bf((float)(vb.y - 128) * s),
                     f2bf((float)(vb.z - 128) * s), f2bf((float)(vb.w - 128) * s) };
        *(u16x4*)(&Bs[row * BK + c4 * 4]) = rb;
      }
    }
    __syncthreads();

    bf16x8 af[4], bfr[4];
    #pragma unroll
    for (int i = 0; i < 4; ++i)
      af[i] = *(const bf16x8*)(As + (wm + i * 16 + lrow) * BK + lq * 8);
    #pragma unroll
    for (int j = 0; j < 4; ++j)
      bfr[j] = *(const bf16x8*)(Bs + (wn + j * 16 + lrow) * BK + lq * 8);
    #pragma unroll
    for (int i = 0; i < 4; ++i)
      #pragma unroll
      for (int j = 0; j < 4; ++j)
        acc[i][j] = __builtin_amdgcn_mfma_f32_16x16x32_bf16(af[i], bfr[j], acc[i][j], 0, 0, 0);
    __syncthreads();
  }

  // epilogue: C/D layout col=lane&15 (n), row=(lane>>4)*4+reg (m)
  #pragma unroll
  for (int i = 0; i < 4; ++i)
    #pragma unroll
    for (int j = 0; j < 4; ++j) {
      int gn = n0 + wn + j * 16 + lrow;
      #pragma unroll
      for (int r = 0; r < 4; ++r) {
        int gm = m0 + wm + i * 16 + lq * 4 + r;
        C[(size_t)gm * N + gn] = acc[i][j][r];
      }
    }
}

extern "C" void kernel_launch(void* const* d_in, const int* in_sizes, int n_in,
                              void* d_out, int out_size, void* d_ws, size_t ws_size,
                              hipStream_t stream) {
  const float* A  = (const float*)d_in[0];
  const int*   Wq = (const int*)d_in[1];
  const float* S  = (const float*)d_in[2];
  float* C = (float*)d_out;

  const int K = 4096;                 // I (infeatures)
  const int N = in_sizes[1] / K;      // O = 4096
  const int M = in_sizes[0] / K;      // B*S = 4096

  const size_t needA = (size_t)M * K * sizeof(u16);
  const size_t needW = (size_t)N * K * sizeof(u16);
  dim3 grid(N / BN, M / BM), blk(256);

  if (ws_size >= needA + needW) {
    u16* Ab = (u16*)d_ws;
    u16* Wb = (u16*)((char*)d_ws + needA);
    size_t nA8 = (size_t)M * K / 8, nW8 = (size_t)N * K / 8;
    cvt_a<<<(int)((nA8 + 255) / 256), 256, 0, stream>>>(A, Ab, nA8);
    cvt_w<<<(int)((nW8 + 255) / 256), 256, 0, stream>>>(Wq, S, Wb, nW8);
    gemm_bt<true><<<grid, blk, 0, stream>>>(Ab, Wb, nullptr, nullptr, nullptr, C, M, N, K);
  } else {
    gemm_bt<false><<<grid, blk, 0, stream>>>(nullptr, nullptr, A, Wq, S, C, M, N, K);
  }
}

// Round 2
// 305.056 us; speedup vs baseline: 1.2156x; 1.2156x over previous
//
#include <hip/hip_runtime.h>
#include <stdint.h>

typedef unsigned short u16;
typedef __bf16 bf16x8 __attribute__((ext_vector_type(8)));
typedef float f32x4 __attribute__((ext_vector_type(4)));
typedef unsigned short u16x8 __attribute__((ext_vector_type(8)));

__device__ __forceinline__ u16 f2bf(float f) {
  union { float f; uint32_t u; } x; x.f = f;
  uint32_t r = x.u + 0x7fffu + ((x.u >> 16) & 1u);   // RNE
  return (u16)(r >> 16);
}

// ---------- fused prologue: A fp32->bf16 and W q8_0->bf16 in one dispatch ----------
__global__ __launch_bounds__(256) void cvt_all(
    const float* __restrict__ A, u16* __restrict__ Ab, size_t n8a,
    const int* __restrict__ Wq, const float* __restrict__ S,
    u16* __restrict__ Wb, size_t n8w) {
  size_t i = (size_t)blockIdx.x * 256 + threadIdx.x;
  if (i < n8a) {
    const float4* p = (const float4*)(A + i * 8);
    float4 v0 = p[0], v1 = p[1];
    u16x8 r = { f2bf(v0.x), f2bf(v0.y), f2bf(v0.z), f2bf(v0.w),
                f2bf(v1.x), f2bf(v1.y), f2bf(v1.z), f2bf(v1.w) };
    *(u16x8*)(Ab + i * 8) = r;
  } else {
    size_t j = i - n8a;
    if (j >= n8w) return;
    const int4* p = (const int4*)(Wq + j * 8);
    int4 v0 = p[0], v1 = p[1];
    float s = S[j >> 2];  // 8 consecutive elems: 4 groups per 32-block
    u16x8 r = { f2bf((float)(v0.x - 128) * s), f2bf((float)(v0.y - 128) * s),
                f2bf((float)(v0.z - 128) * s), f2bf((float)(v0.w - 128) * s),
                f2bf((float)(v1.x - 128) * s), f2bf((float)(v1.y - 128) * s),
                f2bf((float)(v1.z - 128) * s), f2bf((float)(v1.w - 128) * s) };
    *(u16x8*)(Wb + j * 8) = r;
  }
}

// ---------- main GEMM: C[M,N] = A[M,K] * W[N,K]^T, bf16 MFMA ----------
// Block tile 256x128, BK=32, 4 waves, wave tile 128x64 (8x4 of 16x16x32).
#define BM 256
#define BN 128
#define BK 32

__device__ __forceinline__ void load_lds_16B(const void* g, void* l) {
  __builtin_amdgcn_global_load_lds(
      (const __attribute__((address_space(1))) unsigned int*)g,
      (__attribute__((address_space(3))) unsigned int*)l, 16, 0, 0);
}

// MODE 0: A,B bf16 from ws (global_load_lds both)
// MODE 1: A fused fp32->bf16 (VGPR+ds_write), B bf16 from ws
// MODE 2: both fused (no ws)
template <int MODE>
__global__ __launch_bounds__(256, 2) void gemm_mode(
    const u16* __restrict__ Ab, const u16* __restrict__ Wb,
    const float* __restrict__ Af, const int* __restrict__ Wq,
    const float* __restrict__ Sc, float* __restrict__ C,
    int M, int N, int K) {
  __shared__ u16 As[BM * BK];  // 16 KB, row = 32 u16 = 64 B
  __shared__ u16 Bs[BN * BK];  //  8 KB

  const int tid = threadIdx.x;
  const int wave = tid >> 6, lane = tid & 63;
  const int m0 = blockIdx.y * BM, n0 = blockIdx.x * BN;
  const int wm = (wave & 1) * 128, wn = (wave >> 1) * 64;
  const int lrow = lane & 15, lq = lane >> 4;

  // ---- hoisted staging addresses (k0-invariant) ----
  const u16* gA[4]; u16* dA[4];
  const u16* gB[2]; u16* dB[2];
  if constexpr (MODE == 0) {
    #pragma unroll
    for (int it = 0; it < 4; ++it) {        // A: 1024 16B-chunks, 4/wave-lane
      int q = wave * 256 + it * 64 + lane;
      gA[it] = Ab + (size_t)(m0 + (q >> 2)) * K + (q & 3) * 8;
      dA[it] = As + (size_t)(wave * 256 + it * 64) * 8;  // wave-uniform base
    }
  }
  if constexpr (MODE <= 1) {
    #pragma unroll
    for (int it = 0; it < 2; ++it) {        // B: 512 chunks, 2/wave-lane
      int q = wave * 128 + it * 64 + lane;
      gB[it] = Wb + (size_t)(n0 + (q >> 2)) * K + (q & 3) * 8;
      dB[it] = Bs + (size_t)(wave * 128 + it * 64) * 8;
    }
  }

  // ---- hoisted LDS fragment addresses ----
  const u16* fA[8]; const u16* fB[4];
  #pragma unroll
  for (int i = 0; i < 8; ++i) fA[i] = As + (wm + i * 16 + lrow) * BK + lq * 8;
  #pragma unroll
  for (int j = 0; j < 4; ++j) fB[j] = Bs + (wn + j * 16 + lrow) * BK + lq * 8;

  f32x4 acc[8][4] = {};

  for (int k0 = 0; k0 < K; k0 += BK) {
    if constexpr (MODE == 0) {
      #pragma unroll
      for (int it = 0; it < 4; ++it) load_lds_16B(gA[it] + k0, dA[it]);
      #pragma unroll
      for (int it = 0; it < 2; ++it) load_lds_16B(gB[it] + k0, dB[it]);
    } else {
      // fused A: 1024 groups of 8 elems
      #pragma unroll
      for (int it = 0; it < 4; ++it) {
        int g = it * 256 + tid;
        int row = g >> 2, c8 = g & 3;
        const float4* p = (const float4*)(Af + (size_t)(m0 + row) * K + k0 + c8 * 8);
        float4 v0 = p[0], v1 = p[1];
        u16x8 r = { f2bf(v0.x), f2bf(v0.y), f2bf(v0.z), f2bf(v0.w),
                    f2bf(v1.x), f2bf(v1.y), f2bf(v1.z), f2bf(v1.w) };
        *(u16x8*)(As + row * BK + c8 * 8) = r;
      }
      if constexpr (MODE == 1) {
        #pragma unroll
        for (int it = 0; it < 2; ++it) load_lds_16B(gB[it] + k0, dB[it]);
      } else {
        #pragma unroll
        for (int it = 0; it < 2; ++it) {    // fused W: 512 groups
          int g = it * 256 + tid;
          int row = g >> 2, c8 = g & 3;
          const int4* p = (const int4*)(Wq + (size_t)(n0 + row) * K + k0 + c8 * 8);
          int4 v0 = p[0], v1 = p[1];
          float s = Sc[(size_t)(n0 + row) * (K >> 5) + (k0 >> 5)];
          u16x8 r = { f2bf((float)(v0.x - 128) * s), f2bf((float)(v0.y - 128) * s),
                      f2bf((float)(v0.z - 128) * s), f2bf((float)(v0.w - 128) * s),
                      f2bf((float)(v1.x - 128) * s), f2bf((float)(v1.y - 128) * s),
                      f2bf((float)(v1.z - 128) * s), f2bf((float)(v1.w - 128) * s) };
          *(u16x8*)(Bs + row * BK + c8 * 8) = r;
        }
      }
    }
    __syncthreads();

    bf16x8 a[8], b[4];
    #pragma unroll
    for (int i = 0; i < 8; ++i) a[i] = *(const bf16x8*)fA[i];
    #pragma unroll
    for (int j = 0; j < 4; ++j) b[j] = *(const bf16x8*)fB[j];
    #pragma unroll
    for (int i = 0; i < 8; ++i)
      #pragma unroll
      for (int j = 0; j < 4; ++j)
        acc[i][j] = __builtin_amdgcn_mfma_f32_16x16x32_bf16(a[i], b[j], acc[i][j], 0, 0, 0);
    __syncthreads();
  }

  // epilogue: C/D layout col=lane&15 (n), row=(lane>>4)*4+reg (m)
  #pragma unroll
  for (int i = 0; i < 8; ++i) {
    #pragma unroll
    for (int r = 0; r < 4; ++r) {
      int gm = m0 + wm + i * 16 + lq * 4 + r;
      float* crow = C + (size_t)gm * N + n0 + wn + lrow;
      #pragma unroll
      for (int j = 0; j < 4; ++j) crow[j * 16] = acc[i][j][r];
    }
  }
}

extern "C" void kernel_launch(void* const* d_in, const int* in_sizes, int n_in,
                              void* d_out, int out_size, void* d_ws, size_t ws_size,
                              hipStream_t stream) {
  const float* A  = (const float*)d_in[0];
  const int*   Wq = (const int*)d_in[1];
  const float* S  = (const float*)d_in[2];
  float* C = (float*)d_out;

  const int K = 4096;                 // I (infeatures)
  const int N = in_sizes[1] / K;      // O = 4096
  const int M = in_sizes[0] / K;      // B*S = 4096

  const size_t needA = (size_t)M * K * sizeof(u16);   // 32 MB
  const size_t needW = (size_t)N * K * sizeof(u16);   // 32 MB
  dim3 grid(N / BN, M / BM), blk(256);

  if (ws_size >= needA + needW) {
    u16* Ab = (u16*)d_ws;
    u16* Wb = (u16*)((char*)d_ws + needA);
    size_t nA8 = (size_t)M * K / 8, nW8 = (size_t)N * K / 8;
    cvt_all<<<(int)((nA8 + nW8 + 255) / 256), 256, 0, stream>>>(A, Ab, nA8, Wq, S, Wb, nW8);
    gemm_mode<0><<<grid, blk, 0, stream>>>(Ab, Wb, nullptr, nullptr, nullptr, C, M, N, K);
  } else if (ws_size >= needW) {
    u16* Wb = (u16*)d_ws;
    size_t nW8 = (size_t)N * K / 8;
    cvt_all<<<(int)((nW8 + 255) / 256), 256, 0, stream>>>(nullptr, nullptr, 0, Wq, S, Wb, nW8);
    gemm_mode<1><<<grid, blk, 0, stream>>>(nullptr, Wb, A, nullptr, nullptr, C, M, N, K);
  } else {
    gemm_mode<2><<<grid, blk, 0, stream>>>(nullptr, nullptr, A, Wq, S, C, M, N, K);
  }
}

// Round 3
// 302.671 us; speedup vs baseline: 1.2251x; 1.0079x over previous
//
#include <hip/hip_runtime.h>
#include <stdint.h>

typedef unsigned short u16;
typedef __bf16 bf16x8 __attribute__((ext_vector_type(8)));
typedef float f32x4 __attribute__((ext_vector_type(4)));
typedef unsigned short u16x8 __attribute__((ext_vector_type(8)));

__device__ __forceinline__ u16 f2bf(float f) {
  union { float f; uint32_t u; } x; x.f = f;
  uint32_t r = x.u + 0x7fffu + ((x.u >> 16) & 1u);   // RNE
  return (u16)(r >> 16);
}

// ---------- fused prologue: A fp32->bf16 and W q8_0->bf16 in one dispatch ----------
__global__ __launch_bounds__(256) void cvt_all(
    const float* __restrict__ A, u16* __restrict__ Ab, size_t n8a,
    const int* __restrict__ Wq, const float* __restrict__ S,
    u16* __restrict__ Wb, size_t n8w) {
  size_t i = (size_t)blockIdx.x * 256 + threadIdx.x;
  if (i < n8a) {
    const float4* p = (const float4*)(A + i * 8);
    float4 v0 = p[0], v1 = p[1];
    u16x8 r = { f2bf(v0.x), f2bf(v0.y), f2bf(v0.z), f2bf(v0.w),
                f2bf(v1.x), f2bf(v1.y), f2bf(v1.z), f2bf(v1.w) };
    *(u16x8*)(Ab + i * 8) = r;
  } else {
    size_t j = i - n8a;
    if (j >= n8w) return;
    const int4* p = (const int4*)(Wq + j * 8);
    int4 v0 = p[0], v1 = p[1];
    float s = S[j >> 2];  // 8 consecutive elems: 4 groups per 32-block
    u16x8 r = { f2bf((float)(v0.x - 128) * s), f2bf((float)(v0.y - 128) * s),
                f2bf((float)(v0.z - 128) * s), f2bf((float)(v0.w - 128) * s),
                f2bf((float)(v1.x - 128) * s), f2bf((float)(v1.y - 128) * s),
                f2bf((float)(v1.z - 128) * s), f2bf((float)(v1.w - 128) * s) };
    *(u16x8*)(Wb + j * 8) = r;
  }
}

// ---------- main GEMM: C[M,N] = A[M,K] * W[N,K]^T, bf16 MFMA ----------
// Block tile 256x128, BK=32, 4 waves, wave tile 128x64 (8x4 of 16x16x32).
// LDS layout swizzled: slot s of row r holds global 16B-chunk (s - (r>>1)) & 3.
// This spreads fragment ds_read_b128 banks 8-way -> 2-way (free, m136),
// while keeping global_load_lds's dense lane-contiguous LDS destination.
#define BM 256
#define BN 128
#define BK 32

__device__ __forceinline__ void load_lds_16B(const void* g, void* l) {
  __builtin_amdgcn_global_load_lds(
      (const __attribute__((address_space(1))) unsigned int*)g,
      (__attribute__((address_space(3))) unsigned int*)l, 16, 0, 0);
}

// MODE 0: A,B bf16 from ws (global_load_lds both)
// MODE 1: A fused fp32->bf16 (VGPR+ds_write), B bf16 from ws
// MODE 2: both fused (no ws)
template <int MODE>
__global__ __launch_bounds__(256, 2) void gemm_mode(
    const u16* __restrict__ Ab, const u16* __restrict__ Wb,
    const float* __restrict__ Af, const int* __restrict__ Wq,
    const float* __restrict__ Sc, float* __restrict__ C,
    int M, int N, int K) {
  __shared__ u16 As[BM * BK];  // 16 KB, row = 32 u16 = 64 B = 4 chunks of 16 B
  __shared__ u16 Bs[BN * BK];  //  8 KB

  const int tid = threadIdx.x;
  const int wave = tid >> 6, lane = tid & 63;
  const int m0 = blockIdx.y * BM, n0 = blockIdx.x * BN;
  const int wm = (wave & 1) * 128, wn = (wave >> 1) * 64;
  const int lrow = lane & 15, lq = lane >> 4;

  // ---- hoisted staging addresses (k0-invariant) ----
  const u16* gA[4]; u16* dA[4];
  const u16* gB[2]; u16* dB[2];
  if constexpr (MODE == 0) {
    #pragma unroll
    for (int it = 0; it < 4; ++it) {        // A: 1024 16B-chunks, 4/wave-lane
      int q = wave * 256 + it * 64 + lane;
      int row = q >> 2, s = q & 3;
      int c = (s - (row >> 1)) & 3;         // swizzle: global chunk for this slot
      gA[it] = Ab + (size_t)(m0 + row) * K + c * 8;
      dA[it] = As + (size_t)(wave * 256 + it * 64) * 8;  // wave-uniform base
    }
  }
  if constexpr (MODE <= 1) {
    #pragma unroll
    for (int it = 0; it < 2; ++it) {        // B: 512 chunks, 2/wave-lane
      int q = wave * 128 + it * 64 + lane;
      int row = q >> 2, s = q & 3;
      int c = (s - (row >> 1)) & 3;
      gB[it] = Wb + (size_t)(n0 + row) * K + c * 8;
      dB[it] = Bs + (size_t)(wave * 128 + it * 64) * 8;
    }
  }

  // ---- hoisted LDS fragment addresses (swizzled chunk lookup) ----
  const u16* fA[8]; const u16* fB[4];
  #pragma unroll
  for (int i = 0; i < 8; ++i) {
    int row = wm + i * 16 + lrow;
    int s = (lq + (row >> 1)) & 3;
    fA[i] = As + row * BK + s * 8;
  }
  #pragma unroll
  for (int j = 0; j < 4; ++j) {
    int row = wn + j * 16 + lrow;
    int s = (lq + (row >> 1)) & 3;
    fB[j] = Bs + row * BK + s * 8;
  }

  f32x4 acc[8][4] = {};

  for (int k0 = 0; k0 < K; k0 += BK) {
    if constexpr (MODE == 0) {
      #pragma unroll
      for (int it = 0; it < 4; ++it) load_lds_16B(gA[it] + k0, dA[it]);
      #pragma unroll
      for (int it = 0; it < 2; ++it) load_lds_16B(gB[it] + k0, dB[it]);
    } else {
      // fused A: 1024 chunks of 8 elems, written in swizzled layout
      #pragma unroll
      for (int it = 0; it < 4; ++it) {
        int g = it * 256 + tid;
        int row = g >> 2, c8 = g & 3;
        int s = (c8 + (row >> 1)) & 3;
        const float4* p = (const float4*)(Af + (size_t)(m0 + row) * K + k0 + c8 * 8);
        float4 v0 = p[0], v1 = p[1];
        u16x8 r = { f2bf(v0.x), f2bf(v0.y), f2bf(v0.z), f2bf(v0.w),
                    f2bf(v1.x), f2bf(v1.y), f2bf(v1.z), f2bf(v1.w) };
        *(u16x8*)(As + row * BK + s * 8) = r;
      }
      if constexpr (MODE == 1) {
        #pragma unroll
        for (int it = 0; it < 2; ++it) load_lds_16B(gB[it] + k0, dB[it]);
      } else {
        #pragma unroll
        for (int it = 0; it < 2; ++it) {    // fused W: 512 chunks
          int g = it * 256 + tid;
          int row = g >> 2, c8 = g & 3;
          int s = (c8 + (row >> 1)) & 3;
          const int4* p = (const int4*)(Wq + (size_t)(n0 + row) * K + k0 + c8 * 8);
          int4 v0 = p[0], v1 = p[1];
          float sc = Sc[(size_t)(n0 + row) * (K >> 5) + (k0 >> 5)];
          u16x8 r = { f2bf((float)(v0.x - 128) * sc), f2bf((float)(v0.y - 128) * sc),
                      f2bf((float)(v0.z - 128) * sc), f2bf((float)(v0.w - 128) * sc),
                      f2bf((float)(v1.x - 128) * sc), f2bf((float)(v1.y - 128) * sc),
                      f2bf((float)(v1.z - 128) * sc), f2bf((float)(v1.w - 128) * sc) };
          *(u16x8*)(Bs + row * BK + s * 8) = r;
        }
      }
    }
    __syncthreads();

    bf16x8 a[8], b[4];
    #pragma unroll
    for (int i = 0; i < 8; ++i) a[i] = *(const bf16x8*)fA[i];
    #pragma unroll
    for (int j = 0; j < 4; ++j) b[j] = *(const bf16x8*)fB[j];
    #pragma unroll
    for (int i = 0; i < 8; ++i)
      #pragma unroll
      for (int j = 0; j < 4; ++j)
        acc[i][j] = __builtin_amdgcn_mfma_f32_16x16x32_bf16(a[i], b[j], acc[i][j], 0, 0, 0);
    __syncthreads();
  }

  // epilogue: C/D layout col=lane&15 (n), row=(lane>>4)*4+reg (m)
  #pragma unroll
  for (int i = 0; i < 8; ++i) {
    #pragma unroll
    for (int r = 0; r < 4; ++r) {
      int gm = m0 + wm + i * 16 + lq * 4 + r;
      float* crow = C + (size_t)gm * N + n0 + wn + lrow;
      #pragma unroll
      for (int j = 0; j < 4; ++j) crow[j * 16] = acc[i][j][r];
    }
  }
}

extern "C" void kernel_launch(void* const* d_in, const int* in_sizes, int n_in,
                              void* d_out, int out_size, void* d_ws, size_t ws_size,
                              hipStream_t stream) {
  const float* A  = (const float*)d_in[0];
  const int*   Wq = (const int*)d_in[1];
  const float* S  = (const float*)d_in[2];
  float* C = (float*)d_out;

  const int K = 4096;                 // I (infeatures)
  const int N = in_sizes[1] / K;      // O = 4096
  const int M = in_sizes[0] / K;      // B*S = 4096

  const size_t needA = (size_t)M * K * sizeof(u16);   // 32 MB
  const size_t needW = (size_t)N * K * sizeof(u16);   // 32 MB
  dim3 grid(N / BN, M / BM), blk(256);

  if (ws_size >= needA + needW) {
    u16* Ab = (u16*)d_ws;
    u16* Wb = (u16*)((char*)d_ws + needA);
    size_t nA8 = (size_t)M * K / 8, nW8 = (size_t)N * K / 8;
    cvt_all<<<(int)((nA8 + nW8 + 255) / 256), 256, 0, stream>>>(A, Ab, nA8, Wq, S, Wb, nW8);
    gemm_mode<0><<<grid, blk, 0, stream>>>(Ab, Wb, nullptr, nullptr, nullptr, C, M, N, K);
  } else if (ws_size >= needW) {
    u16* Wb = (u16*)d_ws;
    size_t nW8 = (size_t)N * K / 8;
    cvt_all<<<(int)((nW8 + 255) / 256), 256, 0, stream>>>(nullptr, nullptr, 0, Wq, S, Wb, nW8);
    gemm_mode<1><<<grid, blk, 0, stream>>>(nullptr, Wb, A, nullptr, nullptr, C, M, N, K);
  } else {
    gemm_mode<2><<<grid, blk, 0, stream>>>(nullptr, nullptr, A, Wq, S, C, M, N, K);
  }
}